// Round 5
// baseline (120.993 us; speedup 1.0000x reference)
//
#include <hip/hip_runtime.h>

// Problem: inputs [8192, 8192] f32. Semantics: idx = nonzero(x); out = idx.sum(0) -> int64 [2]
//   out[0] = sum of row-index i over nonzeros; out[1] = sum of col-index j over nonzeros.
// Harness reads d_out as int32 (int64 ref wrapped via astype(np.int32)) -> write low 32 bits.

#define DIM1 8192u
#define NBLK 2048u
#define NTHR (NBLK * 256u)          // 524288 threads; 32 float4s each, exact cover
#define N4   (8192u * 8192u / 4u)   // 16777216 float4s

typedef unsigned long long u64;

__device__ __forceinline__ void nz_accum(float4 v, unsigned q,
                                         unsigned& si, unsigned& sj) {
    unsigned i  = q >> 11;                // row index: q / (8192/4)
    unsigned jb = (q << 2) & (DIM1 - 1u); // col index of v.x
    if (v.x != 0.0f) { si += i; sj += jb;      }
    if (v.y != 0.0f) { si += i; sj += jb + 1u; }
    if (v.z != 0.0f) { si += i; sj += jb + 2u; }
    if (v.w != 0.0f) { si += i; sj += jb + 3u; }
}

// launch_bounds(256, 4): VGPR cap 128 (not 64!) so the compiler can keep the
// 8-deep float4 pipeline (32 data VGPRs + addressing) in registers, while
// still guaranteeing >=4 blocks/CU (16 waves/CU). Round 4 showed (256,8)
// clamps to 32 VGPRs -> pipeline serialized -> 645 GB/s. Depth beats width.
__global__ __launch_bounds__(256, 4) void nz_idx_sum_kernel(
    const float4* __restrict__ in, u64* __restrict__ ws, int* __restrict__ out) {
    const unsigned tid = blockIdx.x * 256u + threadIdx.x;
    unsigned si = 0u, sj = 0u;  // per-thread partials fit u32 (max ~1.05e6)

#pragma unroll 1                 // keep rolled: 8 loads in flight per iteration
    for (unsigned g = 0u; g < 4u; ++g) {
        const unsigned qb = tid + g * (8u * NTHR);
        float4 v0 = in[qb];
        float4 v1 = in[qb + 1u * NTHR];
        float4 v2 = in[qb + 2u * NTHR];
        float4 v3 = in[qb + 3u * NTHR];
        float4 v4 = in[qb + 4u * NTHR];
        float4 v5 = in[qb + 5u * NTHR];
        float4 v6 = in[qb + 6u * NTHR];
        float4 v7 = in[qb + 7u * NTHR];
        nz_accum(v0, qb,             si, sj);
        nz_accum(v1, qb + 1u * NTHR, si, sj);
        nz_accum(v2, qb + 2u * NTHR, si, sj);
        nz_accum(v3, qb + 3u * NTHR, si, sj);
        nz_accum(v4, qb + 4u * NTHR, si, sj);
        nz_accum(v5, qb + 5u * NTHR, si, sj);
        nz_accum(v6, qb + 6u * NTHR, si, sj);
        nz_accum(v7, qb + 7u * NTHR, si, sj);
    }

    // wave64 reduce (u32; wave partial max ~6.7e7, fits)
    for (int off = 32; off > 0; off >>= 1) {
        si += __shfl_down(si, off, 64);
        sj += __shfl_down(sj, off, 64);
    }

    __shared__ unsigned s_i[4], s_j[4];
    const int wave = threadIdx.x >> 6;
    const int lane = threadIdx.x & 63;
    if (lane == 0) { s_i[wave] = si; s_j[wave] = sj; }
    __syncthreads();

    if (threadIdx.x == 0) {
        u64 ti = 0, tj = 0;
        for (int w = 0; w < 4; ++w) { ti += (u64)s_i[w]; tj += (u64)s_j[w]; }
        atomicAdd(&ws[0], ti);  // device-scope: safe across XCDs
        atomicAdd(&ws[1], tj);
        __threadfence();        // order my adds before the done-counter bump
        unsigned done = atomicAdd((unsigned*)(ws + 2), 1u);
        if (done == NBLK - 1u) {
            // last block: all partials are in (each block fenced before bumping)
            u64 a = atomicAdd(&ws[0], 0ull);  // atomic read at coherence point
            u64 b = atomicAdd(&ws[1], 0ull);
            out[0] = (int)(unsigned)(a & 0xFFFFFFFFull);  // int64 -> int32 wrap
            out[1] = (int)(unsigned)(b & 0xFFFFFFFFull);
        }
    }
}

extern "C" void kernel_launch(void* const* d_in, const int* in_sizes, int n_in,
                              void* d_out, int out_size, void* d_ws, size_t ws_size,
                              hipStream_t stream) {
    const float4* in = (const float4*)d_in[0];
    u64* ws = (u64*)d_ws;
    int* out = (int*)d_out;

    // zero accumulators + done-counter every call (capture-safe, deterministic;
    // cannot self-reset in-kernel: d_ws is poisoned 0xAA after the correctness call)
    hipMemsetAsync(d_ws, 0, 3 * sizeof(u64), stream);

    nz_idx_sum_kernel<<<NBLK, 256, 0, stream>>>(in, ws, out);
}

// Round 6
// 53.522 us; speedup vs baseline: 2.2606x; 2.2606x over previous
//
#include <hip/hip_runtime.h>

// Problem: inputs [8192, 8192] f32. Semantics: idx = nonzero(x); out = idx.sum(0) -> int64 [2]
//   out[0] = sum of row-index i over nonzeros; out[1] = sum of col-index j over nonzeros.
// Harness reads d_out as int32 (int64 ref wrapped via astype(np.int32)) -> write low 32 bits.
//
// Round 5 lesson: per-block atomicAdds to the SAME cache line (ws[0..2]) serialize at the
// coherence point -> ~tens of us tail. This version: no accumulator atomics at all.
// Each block stores its partial to a private slot; finalize kernel reduces them.

#define DIM1 8192u
#define NBLK 8192u
#define TPB  256u
// Each thread: 8 float4s. 8192 blocks * 256 thr * 8 = 16777216 float4s = exact cover.
// Block b covers float4s [b*2048, (b+1)*2048): per-wave-contiguous 1KB chunks, k*4KB apart.

typedef unsigned long long u64;

__device__ __forceinline__ void nz_accum(float4 v, unsigned q,
                                         unsigned& si, unsigned& sj) {
    unsigned i  = q >> 11;                // row index: q / (8192/4)
    unsigned jb = (q << 2) & (DIM1 - 1u); // col index of v.x
    if (v.x != 0.0f) { si += i; sj += jb;      }
    if (v.y != 0.0f) { si += i; sj += jb + 1u; }
    if (v.z != 0.0f) { si += i; sj += jb + 2u; }
    if (v.w != 0.0f) { si += i; sj += jb + 3u; }
}

// No launch_bounds: let the compiler allocate naturally (~50-70 VGPR) so all 8
// straight-line loads can be issued back-to-back with counted waitcnts.
__global__ void nz_main(const float4* __restrict__ in, uint2* __restrict__ ws) {
    const unsigned q0 = blockIdx.x * 2048u + threadIdx.x;

    // 8 independent coalesced loads, no loop-carried dependence
    float4 v0 = in[q0];
    float4 v1 = in[q0 + 1u * 256u];
    float4 v2 = in[q0 + 2u * 256u];
    float4 v3 = in[q0 + 3u * 256u];
    float4 v4 = in[q0 + 4u * 256u];
    float4 v5 = in[q0 + 5u * 256u];
    float4 v6 = in[q0 + 6u * 256u];
    float4 v7 = in[q0 + 7u * 256u];

    unsigned si = 0u, sj = 0u;  // per-thread max ~32*8191 ~ 262K, fits u32
    nz_accum(v0, q0,             si, sj);
    nz_accum(v1, q0 + 1u * 256u, si, sj);
    nz_accum(v2, q0 + 2u * 256u, si, sj);
    nz_accum(v3, q0 + 3u * 256u, si, sj);
    nz_accum(v4, q0 + 4u * 256u, si, sj);
    nz_accum(v5, q0 + 5u * 256u, si, sj);
    nz_accum(v6, q0 + 6u * 256u, si, sj);
    nz_accum(v7, q0 + 7u * 256u, si, sj);

    // wave64 reduce (u32; wave partial max ~16.8M, fits)
    for (int off = 32; off > 0; off >>= 1) {
        si += __shfl_down(si, off, 64);
        sj += __shfl_down(sj, off, 64);
    }

    __shared__ unsigned s_i[4], s_j[4];
    const int wave = threadIdx.x >> 6;
    const int lane = threadIdx.x & 63;
    if (lane == 0) { s_i[wave] = si; s_j[wave] = sj; }
    __syncthreads();

    if (threadIdx.x == 0) {
        // block partial max ~67M, fits u32. Private slot -> no contention, no atomics.
        unsigned ti = s_i[0] + s_i[1] + s_i[2] + s_i[3];
        unsigned tj = s_j[0] + s_j[1] + s_j[2] + s_j[3];
        ws[blockIdx.x] = make_uint2(ti, tj);   // plain store; fully overwritten every call
    }
}

__global__ void nz_finalize(const uint2* __restrict__ ws, int* __restrict__ out) {
    u64 ti = 0, tj = 0;
    for (unsigned j = threadIdx.x; j < NBLK; j += TPB) {  // 32 coalesced uint2 loads
        uint2 p = ws[j];
        ti += p.x;
        tj += p.y;
    }
    for (int off = 32; off > 0; off >>= 1) {
        ti += __shfl_down(ti, off, 64);
        tj += __shfl_down(tj, off, 64);
    }
    __shared__ u64 s_i[4], s_j[4];
    const int wave = threadIdx.x >> 6;
    const int lane = threadIdx.x & 63;
    if (lane == 0) { s_i[wave] = ti; s_j[wave] = tj; }
    __syncthreads();
    if (threadIdx.x == 0) {
        u64 a = s_i[0] + s_i[1] + s_i[2] + s_i[3];
        u64 b = s_j[0] + s_j[1] + s_j[2] + s_j[3];
        out[0] = (int)(unsigned)(a & 0xFFFFFFFFull);  // int64 -> int32 wrap
        out[1] = (int)(unsigned)(b & 0xFFFFFFFFull);
    }
}

extern "C" void kernel_launch(void* const* d_in, const int* in_sizes, int n_in,
                              void* d_out, int out_size, void* d_ws, size_t ws_size,
                              hipStream_t stream) {
    const float4* in = (const float4*)d_in[0];
    uint2* ws = (uint2*)d_ws;   // needs 8192*8 = 64 KB of scratch
    int* out = (int*)d_out;

    // No memset needed: every ws slot is overwritten by nz_main each call.
    nz_main<<<NBLK, TPB, 0, stream>>>(in, ws);
    nz_finalize<<<1, TPB, 0, stream>>>(ws, out);
}

// Round 7
// 49.694 us; speedup vs baseline: 2.4347x; 1.0770x over previous
//
#include <hip/hip_runtime.h>

// Problem: inputs [8192, 8192] f32. Semantics: idx = nonzero(x); out = idx.sum(0) -> int64 [2]
//   out[0] = sum of row-index i over nonzeros; out[1] = sum of col-index j over nonzeros.
// Harness reads d_out as int32 (int64 ref wrapped via astype(np.int32)) -> write low 32 bits.
//
// R5 lesson: same-cache-line atomics serialize (~tens of us) -> per-block private slots.
// R6 lesson: straight-line independent loads DO get scheduled back-to-back (53.5 us);
//            rolled loops got pairwise load/consume interleave (32 VGPR, 120 us).
// R7: double MLP depth to 16 float4s/thread straight-line.

#define DIM1 8192u
#define NBLK 4096u
#define TPB  256u
// 4096 blocks * 256 thr * 16 float4 = 16777216 float4s = exact cover.
// Block b covers float4s [b*4096, (b+1)*4096); thread strides of 256 f4 = 4KB.

typedef unsigned long long u64;

__device__ __forceinline__ void nz_accum(float4 v, unsigned q,
                                         unsigned& si, unsigned& sj) {
    unsigned i  = q >> 11;                // row index: q / (8192/4)
    unsigned jb = (q << 2) & (DIM1 - 1u); // col index of v.x
    if (v.x != 0.0f) { si += i; sj += jb;      }
    if (v.y != 0.0f) { si += i; sj += jb + 1u; }
    if (v.z != 0.0f) { si += i; sj += jb + 2u; }
    if (v.w != 0.0f) { si += i; sj += jb + 3u; }
}

// No launch_bounds: natural allocation (~100 VGPR) keeps 16 loads in flight
// at ~5 waves/SIMD. (256,8) clamped to 32 VGPR and serialized loads (R4/R5).
__global__ void nz_main(const float4* __restrict__ in, uint2* __restrict__ ws) {
    const unsigned q0 = blockIdx.x * 4096u + threadIdx.x;

    // 16 independent coalesced loads, straight-line, no loop-carried dependence
    float4 v0  = in[q0];
    float4 v1  = in[q0 + 1u  * 256u];
    float4 v2  = in[q0 + 2u  * 256u];
    float4 v3  = in[q0 + 3u  * 256u];
    float4 v4  = in[q0 + 4u  * 256u];
    float4 v5  = in[q0 + 5u  * 256u];
    float4 v6  = in[q0 + 6u  * 256u];
    float4 v7  = in[q0 + 7u  * 256u];
    float4 v8  = in[q0 + 8u  * 256u];
    float4 v9  = in[q0 + 9u  * 256u];
    float4 v10 = in[q0 + 10u * 256u];
    float4 v11 = in[q0 + 11u * 256u];
    float4 v12 = in[q0 + 12u * 256u];
    float4 v13 = in[q0 + 13u * 256u];
    float4 v14 = in[q0 + 14u * 256u];
    float4 v15 = in[q0 + 15u * 256u];

    unsigned si = 0u, sj = 0u;  // per-thread max ~64*8191 ~ 524K, fits u32
    nz_accum(v0,  q0,              si, sj);
    nz_accum(v1,  q0 + 1u  * 256u, si, sj);
    nz_accum(v2,  q0 + 2u  * 256u, si, sj);
    nz_accum(v3,  q0 + 3u  * 256u, si, sj);
    nz_accum(v4,  q0 + 4u  * 256u, si, sj);
    nz_accum(v5,  q0 + 5u  * 256u, si, sj);
    nz_accum(v6,  q0 + 6u  * 256u, si, sj);
    nz_accum(v7,  q0 + 7u  * 256u, si, sj);
    nz_accum(v8,  q0 + 8u  * 256u, si, sj);
    nz_accum(v9,  q0 + 9u  * 256u, si, sj);
    nz_accum(v10, q0 + 10u * 256u, si, sj);
    nz_accum(v11, q0 + 11u * 256u, si, sj);
    nz_accum(v12, q0 + 12u * 256u, si, sj);
    nz_accum(v13, q0 + 13u * 256u, si, sj);
    nz_accum(v14, q0 + 14u * 256u, si, sj);
    nz_accum(v15, q0 + 15u * 256u, si, sj);

    // wave64 reduce (u32; wave partial max ~33.5M, fits)
    for (int off = 32; off > 0; off >>= 1) {
        si += __shfl_down(si, off, 64);
        sj += __shfl_down(sj, off, 64);
    }

    __shared__ unsigned s_i[4], s_j[4];
    const int wave = threadIdx.x >> 6;
    const int lane = threadIdx.x & 63;
    if (lane == 0) { s_i[wave] = si; s_j[wave] = sj; }
    __syncthreads();

    if (threadIdx.x == 0) {
        // block partial max ~134M, fits u32. Private slot: no contention, no atomics.
        unsigned ti = s_i[0] + s_i[1] + s_i[2] + s_i[3];
        unsigned tj = s_j[0] + s_j[1] + s_j[2] + s_j[3];
        ws[blockIdx.x] = make_uint2(ti, tj);   // plain store; fully overwritten every call
    }
}

__global__ void nz_finalize(const uint2* __restrict__ ws, int* __restrict__ out) {
    u64 ti = 0, tj = 0;
    for (unsigned j = threadIdx.x; j < NBLK; j += TPB) {  // 16 coalesced uint2 loads
        uint2 p = ws[j];
        ti += p.x;
        tj += p.y;
    }
    for (int off = 32; off > 0; off >>= 1) {
        ti += __shfl_down(ti, off, 64);
        tj += __shfl_down(tj, off, 64);
    }
    __shared__ u64 s_i[4], s_j[4];
    const int wave = threadIdx.x >> 6;
    const int lane = threadIdx.x & 63;
    if (lane == 0) { s_i[wave] = ti; s_j[wave] = tj; }
    __syncthreads();
    if (threadIdx.x == 0) {
        u64 a = s_i[0] + s_i[1] + s_i[2] + s_i[3];
        u64 b = s_j[0] + s_j[1] + s_j[2] + s_j[3];
        out[0] = (int)(unsigned)(a & 0xFFFFFFFFull);  // int64 -> int32 wrap
        out[1] = (int)(unsigned)(b & 0xFFFFFFFFull);
    }
}

extern "C" void kernel_launch(void* const* d_in, const int* in_sizes, int n_in,
                              void* d_out, int out_size, void* d_ws, size_t ws_size,
                              hipStream_t stream) {
    const float4* in = (const float4*)d_in[0];
    uint2* ws = (uint2*)d_ws;   // needs 4096*8 = 32 KB of scratch
    int* out = (int*)d_out;

    // No memset needed: every ws slot is overwritten by nz_main each call.
    nz_main<<<NBLK, TPB, 0, stream>>>(in, ws);
    nz_finalize<<<1, TPB, 0, stream>>>(ws, out);
}